// Round 14
// baseline (52.986 us; speedup 1.0000x reference)
//
#include <hip/hip_runtime.h>

namespace {
constexpr int kNP = 8, kNR = 12;
constexpr int kRelCell = 288;          // NP*K*NR floats per cell (1152 B)
constexpr int kH = 64, kNOUT = 64;
constexpr int CELLS = 4;               // cells per wave
constexpr int WT_LD = 65;              // padded: conflict-free
}

__device__ __forceinline__ float readlane_f(float v, int l) {
    union { float f; int i; } u; u.f = v;
    u.i = __builtin_amdgcn_readlane(u.i, l);
    return u.f;
}

// DPP add step on the VALU pipe; invalid source lanes contribute 0.
template<int CTRL>
__device__ __forceinline__ float dpp_add(float x) {
    int y = __builtin_amdgcn_update_dpp(0, __float_as_int(x), CTRL, 0xf, 0xf, true);
    return x + __int_as_float(y);
}
// 64-lane sum (no DS ops); lane 63 holds the total.
__device__ __forceinline__ float wave_sum63(float x) {
    x = dpp_add<0x111>(x);  // row_shr:1
    x = dpp_add<0x112>(x);  // row_shr:2
    x = dpp_add<0x114>(x);  // row_shr:4
    x = dpp_add<0x118>(x);  // row_shr:8
    x = dpp_add<0x142>(x);  // row_bcast:15
    x = dpp_add<0x143>(x);  // row_bcast:31
    return x;
}

// L2-warming prefetch of one 288-float cell: float4 covers floats 0..255,
// dword covers 224..287 -- complete, no OOB past the cell.
__device__ __forceinline__ void pf_issue(const float* cb, int lane,
                                         float4* a, float* b) {
    *a = *(const float4*)(cb + lane * 4);
    *b = cb[224 + lane];
}
// keep prefetch registers alive (placed AFTER older compute: waitcnt satisfied)
#define PF_SINK(a, b) asm volatile("" :: "v"((a).x), "v"((a).y), "v"((a).z), "v"((a).w), "v"(b))

// One cell's logits+softmax+combine; cb is wave-uniform -> scalar s_load path.
// wz2 pre-scaled by log2(e); raw v_exp_f32, no max subtraction (logits bounded
// far below exp2's 127 overflow), v_rcp vs precise divide (1 ulp, threshold 0.2%).
__device__ __forceinline__ float cell_z(const float* __restrict__ cb,
                                        const float* __restrict__ dreg,
                                        float sv_i, float wz2) {
    float zj[kNP], la[kNP];
#pragma unroll
    for (int p = 0; p < kNP; ++p) {
        const float4* r4 = (const float4*)(cb + p * 36);
        const float4 a0 = r4[0], a1 = r4[1], a2 = r4[2];
        const float4 b0 = r4[3], b1 = r4[4], b2 = r4[5];
        const float4 c0 = r4[6], c1 = r4[7], c2 = r4[8];
        float d0 = a0.x*dreg[0] + a0.y*dreg[1] + a0.z*dreg[2] + a0.w*dreg[3]
                 + a1.x*dreg[4] + a1.y*dreg[5] + a1.z*dreg[6] + a1.w*dreg[7]
                 + a2.x*dreg[8] + a2.y*dreg[9] + a2.z*dreg[10] + a2.w*dreg[11];
        float d1 = b0.x*dreg[0] + b0.y*dreg[1] + b0.z*dreg[2] + b0.w*dreg[3]
                 + b1.x*dreg[4] + b1.y*dreg[5] + b1.z*dreg[6] + b1.w*dreg[7]
                 + b2.x*dreg[8] + b2.y*dreg[9] + b2.z*dreg[10] + b2.w*dreg[11];
        float d2 = c0.x*dreg[0] + c0.y*dreg[1] + c0.z*dreg[2] + c0.w*dreg[3]
                 + c1.x*dreg[4] + c1.y*dreg[5] + c1.z*dreg[6] + c1.w*dreg[7]
                 + c2.x*dreg[8] + c2.y*dreg[9] + c2.z*dreg[10] + c2.w*dreg[11];
        const float z = d0 * d1 * d2 * sv_i;
        zj[p] = z;
        la[p] = z * wz2;
    }
#pragma unroll
    for (int p = 0; p < kNP; ++p) la[p] = wave_sum63(la[p]);
    float esum = 0.f, zd = 0.f;
#pragma unroll
    for (int p = 0; p < kNP; ++p) {
        const float e = __builtin_amdgcn_exp2f(readlane_f(la[p], 63));
        esum += e;
        zd = fmaf(e, zj[p], zd);
    }
    return zd * __builtin_amdgcn_rcpf(esum);
}

// grid: 128 (b,v) x 16 f = 2048 blocks of 256 threads; wave w -> t = 4w..4w+3.
// Round-13 data path; NEW: NO barrier before the cell loop. dreg comes from a
// direct global gather (L2-resident Wstack, round-8-proven), so cells depend
// only on global loads issued from instruction 1; waves enter the scalar-
// latency region staggered instead of lockstep. Single wT barrier moved to
// just before the epilogue (its only consumer). LDS 17.25 KB.
__global__ __launch_bounds__(256, 4) void gal_kernel(
    const float* __restrict__ rel,      // (BS,NV,MF,MT,NP,K,NR)
    const float* __restrict__ se,       // (BS,NV,MT,MF,H)
    const float* __restrict__ s,        // unused (cancels in softmax)
    const float* __restrict__ Wstack,   // (NR,H,H)
    const float* __restrict__ lin_w,    // (1,H+NOUT)
    const float* __restrict__ lin_b,    // unused (cancels)
    const float* __restrict__ out_w,    // (NOUT,H)
    const float* __restrict__ out_b,    // (NOUT,)
    float* __restrict__ out)            // (BS,NV,NOUT)
{
    __shared__ __align__(16) float wT[kH * WT_LD];  // 16.25 KB
    __shared__ __align__(16) float redbuf[256];     // 1 KB

    const int tid  = (int)threadIdx.x;
    const int lane = tid & 63;
    const int w    = __builtin_amdgcn_readfirstlane(tid >> 6);  // uniform wave id

    const int bv = (int)blockIdx.x >> 4;   // 0..127
    const int f  = (int)blockIdx.x & 15;
    const int t0 = w * CELLS;

    const float* relbase = rel + ((size_t)((bv * 16 + f) * 16) + t0) * kRelCell;

    // prefetch cells 0,1 immediately
    float4 pfa0, pfa1, pfa2, pfa3; float pfb0, pfb1, pfb2, pfb3;
    pf_issue(relbase,            lane, &pfa0, &pfb0);
    pf_issue(relbase + kRelCell, lane, &pfa1, &pfb1);

    // out_w (o,d) -> wT[d*65+o]; stride-65 writes -> distinct banks.
    // Consumed only by the epilogue; barrier is down there.
    for (int i = tid; i < kH * kNOUT; i += 256) {
        const int o = i >> 6, d = i & 63;
        wT[d * WT_LD + o] = out_w[i];
    }

    // dreg: direct per-lane gather (stride-65 dwords, Wstack L2-resident)
    float dreg[kNR];
#pragma unroll
    for (int r = 0; r < kNR; ++r)
        dreg[r] = Wstack[r * kH * kH + lane * (kH + 1)];

    const float wz2 = lin_w[kNOUT + lane] * 1.44269504088896340736f;  // log2(e)
    const float ob = out_b[lane];   // lane = o in epilogue
    const float* sep = se + ((size_t)(bv * 16 + t0) * 16 + f) * kH + lane;
    float sev[CELLS];
#pragma unroll
    for (int i = 0; i < CELLS; ++i) sev[i] = sep[(size_t)i * (16 * kH)];

    // ---- cell loop: no barrier above; scalar chains start ASAP ----
    float zreg[CELLS];
    pf_issue(relbase + 2 * kRelCell, lane, &pfa2, &pfb2);
    zreg[0] = cell_z(relbase,                dreg, sev[0], wz2);
    PF_SINK(pfa0, pfb0);
    pf_issue(relbase + 3 * kRelCell, lane, &pfa3, &pfb3);
    zreg[1] = cell_z(relbase + 1 * kRelCell, dreg, sev[1], wz2);
    PF_SINK(pfa1, pfb1);
    zreg[2] = cell_z(relbase + 2 * kRelCell, dreg, sev[2], wz2);
    PF_SINK(pfa2, pfb2);
    zreg[3] = cell_z(relbase + 3 * kRelCell, dreg, sev[3], wz2);
    PF_SINK(pfa3, pfb3);

    __syncthreads();   // wT writes (all waves) visible to epilogue reads

    // epilogue: batched 64x64 matvec over 4 cells; lane = o
    float q[CELLS];
#pragma unroll
    for (int i = 0; i < CELLS; ++i) q[i] = 0.f;
#pragma unroll
    for (int d = 0; d < kH; ++d) {
        const float wv = wT[d * WT_LD + lane];
#pragma unroll
        for (int i = 0; i < CELLS; ++i)
            q[i] = fmaf(readlane_f(zreg[i], d), wv, q[i]);
    }
    float tot = 0.f;
#pragma unroll
    for (int i = 0; i < CELLS; ++i) tot += fmaxf(q[i] + ob, 0.f);

    // block reduce -> one wave-atomic per block
    redbuf[w * 64 + lane] = tot;
    __syncthreads();
    if (w == 0) {
        const float r = redbuf[lane] + redbuf[64 + lane]
                      + redbuf[128 + lane] + redbuf[192 + lane];
        atomicAdd(&out[bv * kNOUT + lane], r);
    }
}

extern "C" void kernel_launch(void* const* d_in, const int* in_sizes, int n_in,
                              void* d_out, int out_size, void* d_ws, size_t ws_size,
                              hipStream_t stream) {
    const float* rel   = (const float*)d_in[0];
    const float* sem   = (const float*)d_in[1];
    const float* s     = (const float*)d_in[2];
    const float* Wst   = (const float*)d_in[3];
    const float* lin_w = (const float*)d_in[4];
    const float* lin_b = (const float*)d_in[5];
    const float* out_w = (const float*)d_in[6];
    const float* out_b = (const float*)d_in[7];
    float* out = (float*)d_out;

    hipMemsetAsync(out, 0, sizeof(float) * 8 * 16 * kNOUT, stream);
    dim3 grid(2048), block(256);
    hipLaunchKernelGGL(gal_kernel, grid, block, 0, stream,
                       rel, sem, s, Wst, lin_w, lin_b, out_w, out_b, out);
}

// Round 15
// 45.024 us; speedup vs baseline: 1.1768x; 1.1768x over previous
//
#include <hip/hip_runtime.h>

namespace {
constexpr int kNP = 8, kNR = 12;
constexpr int kRelCell = 288;          // NP*K*NR floats per cell (1152 B)
constexpr int kH = 64, kNOUT = 64;
constexpr int CELLS = 2;               // cells per wave
constexpr int WAVES = 8;               // 512-thread blocks
constexpr int WT_LD = 65;              // padded: conflict-free
}

__device__ __forceinline__ float readlane_f(float v, int l) {
    union { float f; int i; } u; u.f = v;
    u.i = __builtin_amdgcn_readlane(u.i, l);
    return u.f;
}

// DPP add step on the VALU pipe; invalid source lanes contribute 0.
template<int CTRL>
__device__ __forceinline__ float dpp_add(float x) {
    int y = __builtin_amdgcn_update_dpp(0, __float_as_int(x), CTRL, 0xf, 0xf, true);
    return x + __int_as_float(y);
}
// 64-lane sum (no DS ops); lane 63 holds the total.
__device__ __forceinline__ float wave_sum63(float x) {
    x = dpp_add<0x111>(x);  // row_shr:1
    x = dpp_add<0x112>(x);  // row_shr:2
    x = dpp_add<0x114>(x);  // row_shr:4
    x = dpp_add<0x118>(x);  // row_shr:8
    x = dpp_add<0x142>(x);  // row_bcast:15
    x = dpp_add<0x143>(x);  // row_bcast:31
    return x;
}

// L2-warming prefetch of one 288-float cell: float4 covers floats 0..255,
// dword covers 224..287 -- complete, no OOB past the cell.
__device__ __forceinline__ void pf_issue(const float* cb, int lane,
                                         float4* a, float* b) {
    *a = *(const float4*)(cb + lane * 4);
    *b = cb[224 + lane];
}
// keep prefetch registers alive (placed AFTER older compute: waitcnt satisfied)
#define PF_SINK(a, b) asm volatile("" :: "v"((a).x), "v"((a).y), "v"((a).z), "v"((a).w), "v"(b))

// One cell's logits+softmax+combine; cb is wave-uniform -> scalar s_load path.
// wz2 pre-scaled by log2(e); raw v_exp_f32, no max subtraction (logits bounded
// far below exp2's 127 overflow), v_rcp vs precise divide (1 ulp, thr 0.2%).
__device__ __forceinline__ float cell_z(const float* __restrict__ cb,
                                        const float* __restrict__ dreg,
                                        float sv_i, float wz2) {
    float zj[kNP], la[kNP];
#pragma unroll
    for (int p = 0; p < kNP; ++p) {
        const float4* r4 = (const float4*)(cb + p * 36);
        const float4 a0 = r4[0], a1 = r4[1], a2 = r4[2];
        const float4 b0 = r4[3], b1 = r4[4], b2 = r4[5];
        const float4 c0 = r4[6], c1 = r4[7], c2 = r4[8];
        float d0 = a0.x*dreg[0] + a0.y*dreg[1] + a0.z*dreg[2] + a0.w*dreg[3]
                 + a1.x*dreg[4] + a1.y*dreg[5] + a1.z*dreg[6] + a1.w*dreg[7]
                 + a2.x*dreg[8] + a2.y*dreg[9] + a2.z*dreg[10] + a2.w*dreg[11];
        float d1 = b0.x*dreg[0] + b0.y*dreg[1] + b0.z*dreg[2] + b0.w*dreg[3]
                 + b1.x*dreg[4] + b1.y*dreg[5] + b1.z*dreg[6] + b1.w*dreg[7]
                 + b2.x*dreg[8] + b2.y*dreg[9] + b2.z*dreg[10] + b2.w*dreg[11];
        float d2 = c0.x*dreg[0] + c0.y*dreg[1] + c0.z*dreg[2] + c0.w*dreg[3]
                 + c1.x*dreg[4] + c1.y*dreg[5] + c1.z*dreg[6] + c1.w*dreg[7]
                 + c2.x*dreg[8] + c2.y*dreg[9] + c2.z*dreg[10] + c2.w*dreg[11];
        const float z = d0 * d1 * d2 * sv_i;
        zj[p] = z;
        la[p] = z * wz2;
    }
#pragma unroll
    for (int p = 0; p < kNP; ++p) la[p] = wave_sum63(la[p]);
    float esum = 0.f, zd = 0.f;
#pragma unroll
    for (int p = 0; p < kNP; ++p) {
        const float e = __builtin_amdgcn_exp2f(readlane_f(la[p], 63));
        esum += e;
        zd = fmaf(e, zj[p], zd);
    }
    return zd * __builtin_amdgcn_rcpf(esum);
}

// grid: 128 (b,v) x 16 f = 2048 blocks of 512 threads (8 waves); wave w ->
// t = 2w..2w+1. Round-13 data path (champion), but CELLS 4->2 and WAVES 4->8:
// per-wave serial scalar-batch chain halves, wave count doubles, wT/diag
// amortization per block unchanged. LDS 19.7 KB -> 4 blocks/CU x 8 waves =
// 32 waves/CU (100% static occupancy). Live state shrinks (zreg[2], 2 pf sets).
__global__ __launch_bounds__(512, 4) void gal_kernel(
    const float* __restrict__ rel,      // (BS,NV,MF,MT,NP,K,NR)
    const float* __restrict__ se,       // (BS,NV,MT,MF,H)
    const float* __restrict__ s,        // unused (cancels in softmax)
    const float* __restrict__ Wstack,   // (NR,H,H)
    const float* __restrict__ lin_w,    // (1,H+NOUT)
    const float* __restrict__ lin_b,    // unused (cancels)
    const float* __restrict__ out_w,    // (NOUT,H)
    const float* __restrict__ out_b,    // (NOUT,)
    float* __restrict__ out)            // (BS,NV,NOUT)
{
    __shared__ __align__(16) float wT[kH * WT_LD];     // 16.25 KB
    __shared__ __align__(16) float dshare[kNR * kH];   // 3 KB diag; reused as redbuf (512 used)

    const int tid  = (int)threadIdx.x;
    const int lane = tid & 63;
    const int w    = __builtin_amdgcn_readfirstlane(tid >> 6);  // uniform wave id 0..7

    const int bv = (int)blockIdx.x >> 4;   // 0..127
    const int f  = (int)blockIdx.x & 15;
    const int t0 = w * CELLS;

    const float* relbase = rel + ((size_t)((bv * 16 + f) * 16) + t0) * kRelCell;

    // prefetch both cells immediately (overlap whole prologue; drain at B1)
    float4 pfa0, pfa1; float pfb0, pfb1;
    pf_issue(relbase,            lane, &pfa0, &pfb0);
    pf_issue(relbase + kRelCell, lane, &pfa1, &pfb1);

    // out_w (o,d) -> wT[d*65+o]; stride-65 writes -> distinct banks
    for (int i = tid; i < kH * kNOUT; i += 512) {
        const int o = i >> 6, d = i & 63;
        wT[d * WT_LD + o] = out_w[i];
    }
    // diag gather (stride-65 in Wstack) once per block
    for (int i = tid; i < kNR * kH; i += 512) {
        const int r = i >> 6, d = i & 63;
        dshare[i] = Wstack[r * kH * kH + d * (kH + 1)];
    }

    const float wz2 = lin_w[kNOUT + lane] * 1.44269504088896340736f;  // log2(e)
    const float ob = out_b[lane];   // lane = o in epilogue
    const float* sep = se + ((size_t)(bv * 16 + t0) * 16 + f) * kH + lane;
    float sev[CELLS];
#pragma unroll
    for (int i = 0; i < CELLS; ++i) sev[i] = sep[(size_t)i * (16 * kH)];

    __syncthreads();                 // B1: wT + dshare staged (+ prefetch drained)
    float dreg[kNR];
#pragma unroll
    for (int r = 0; r < kNR; ++r) dreg[r] = dshare[r * kH + lane];  // stride-1
    __syncthreads();                 // B2: diag consumed -> dshare free for redbuf

    float zreg[CELLS];
    zreg[0] = cell_z(relbase,            dreg, sev[0], wz2);
    PF_SINK(pfa0, pfb0);
    zreg[1] = cell_z(relbase + kRelCell, dreg, sev[1], wz2);
    PF_SINK(pfa1, pfb1);

    // epilogue: batched 64x64 matvec over 2 cells; lane = o
    float q0 = 0.f, q1 = 0.f;
#pragma unroll
    for (int d = 0; d < kH; ++d) {
        const float wv = wT[d * WT_LD + lane];
        q0 = fmaf(readlane_f(zreg[0], d), wv, q0);
        q1 = fmaf(readlane_f(zreg[1], d), wv, q1);
    }
    const float tot = fmaxf(q0 + ob, 0.f) + fmaxf(q1 + ob, 0.f);

    // block reduce (dshare[0..511] reused) -> one wave-atomic per block
    dshare[w * 64 + lane] = tot;
    __syncthreads();                 // B3
    if (w == 0) {
        float r = 0.f;
#pragma unroll
        for (int j = 0; j < WAVES; ++j) r += dshare[j * 64 + lane];
        atomicAdd(&out[bv * kNOUT + lane], r);
    }
}

extern "C" void kernel_launch(void* const* d_in, const int* in_sizes, int n_in,
                              void* d_out, int out_size, void* d_ws, size_t ws_size,
                              hipStream_t stream) {
    const float* rel   = (const float*)d_in[0];
    const float* sem   = (const float*)d_in[1];
    const float* s     = (const float*)d_in[2];
    const float* Wst   = (const float*)d_in[3];
    const float* lin_w = (const float*)d_in[4];
    const float* lin_b = (const float*)d_in[5];
    const float* out_w = (const float*)d_in[6];
    const float* out_b = (const float*)d_in[7];
    float* out = (float*)d_out;

    hipMemsetAsync(out, 0, sizeof(float) * 8 * 16 * kNOUT, stream);
    dim3 grid(2048), block(512);
    hipLaunchKernelGGL(gal_kernel, grid, block, 0, stream,
                       rel, sem, s, Wst, lin_w, lin_b, out_w, out_b, out);
}